// Round 4
// baseline (422.101 us; speedup 1.0000x reference)
//
#include <hip/hip_runtime.h>
#include <math.h>

// Problem constants
#define N_ROWS   131072      // 32*64*64 pixels
#define DIM      64          // embedding dim
#define KCODES   1024        // codebook entries
#define HWSZ     4096        // 64*64
#define CHW      262144      // 64*64*64 (per-batch NCHW stride)
#define OUT_ELEMS 8388608    // 32*64*64*64
#define BLOCK    512         // 8 waves: halves split the codebook (split-K)
#define HALF_T   256         // threads per half
#define PIX      2           // pixels per thread (packed as v2f for v_pk_fma_f32)
#define PIXBLK   (HALF_T * PIX)       // 512 pixels per block
#define NBLOCKS  (N_ROWS / PIXBLK)    // 256 -> exactly 1 block/CU, 8 waves = 2/SIMD
#define KHALF    512         // codes per half

typedef float v2f __attribute__((ext_vector_type(2)));

// packed fma: both pixel chains advance one d with one (hopefully pk) fma.
// Each component is an independent scalar fmaf chain -> bit-identical.
__device__ __forceinline__ v2f fma2(v2f a, float b, v2f c) {
#if __has_builtin(__builtin_elementwise_fma)
    v2f bb = {b, b};
    return __builtin_elementwise_fma(a, bb, c);
#else
    v2f r;
    r[0] = __builtin_fmaf(a[0], b, c[0]);
    r[1] = __builtin_fmaf(a[1], b, c[1]);
    return r;
#endif
}

// ---------------------------------------------------------------------------
// numpy pairwise sum of squares, n=64 (8-accumulator block, scalar order).
// Bit-exact np.sum(v**2, axis=-1); contract(off) keeps mul/add separate.
// ---------------------------------------------------------------------------
__device__ __forceinline__ float np_sumsq64(const float* v) {
#pragma clang fp contract(off)
    float r[8];
#pragma unroll
    for (int j = 0; j < 8; ++j) r[j] = v[j] * v[j];
#pragma unroll
    for (int i = 8; i < 64; i += 8) {
#pragma unroll
        for (int j = 0; j < 8; ++j) {
            float p = v[i + j] * v[i + j];
            r[j] = r[j] + p;
        }
    }
    float s01 = r[0] + r[1];
    float s23 = r[2] + r[3];
    float s45 = r[4] + r[5];
    float s67 = r[6] + r[7];
    return (s01 + s23) + (s45 + s67);
}

// Same chain but over component `off` of a v2f[64] array (stride-2 floats).
// Identical value sequence/order as np_sumsq64 on the unpacked array.
__device__ __forceinline__ float np_sumsq64_s2(const float* v, int off) {
#pragma clang fp contract(off)
    float r[8];
#pragma unroll
    for (int j = 0; j < 8; ++j) {
        const float t = v[2 * j + off];
        r[j] = t * t;
    }
#pragma unroll
    for (int i = 8; i < 64; i += 8) {
#pragma unroll
        for (int j = 0; j < 8; ++j) {
            const float t = v[2 * (i + j) + off];
            const float p = t * t;
            r[j] = r[j] + p;
        }
    }
    float s01 = r[0] + r[1];
    float s23 = r[2] + r[3];
    float s45 = r[4] + r[5];
    float s67 = r[6] + r[7];
    return (s01 + s23) + (s45 + s67);
}

// ---------------------------------------------------------------------------
// Kernel 0: per-code ||w_k||^2 (numpy-pairwise) -> ws[0..1023]
// ---------------------------------------------------------------------------
__global__ __launch_bounds__(256) void vq_wsum(const float* __restrict__ w,
                                               float* __restrict__ wsum) {
    int k = blockIdx.x * blockDim.x + threadIdx.x;   // grid = 4*256 = 1024
    const float* wr = w + k * DIM;
    float wv[DIM];
#pragma unroll
    for (int d = 0; d < DIM; ++d) wv[d] = wr[d];
    wsum[k] = np_sumsq64(wv);
}

// ---------------------------------------------------------------------------
// Kernel 1: main VQ — scalar-path weights.
//   - Weights are wave-uniform (all lanes sweep the same code): `half` is
//     readfirstlane'd so all w/wsum addresses are provably uniform -> the
//     compiler materializes them as s_load into SGPRs, feeding v_fma's one
//     scalar operand. NO LDS staging, NO main-loop barriers, zero LDS pipe
//     load (round-3 diagnosis: LDS return BW was co-saturated with VALU).
//   - 2 pixels packed in v2f -> v_pk_fma_f32 halves VALU issue.
//   - A/B 32-float SGPR buffers software-pipeline the scalar load stream.
//   - split-K across block halves (codes 0..511 / 512..1023), 8 waves/CU.
//   Numerics BIT-IDENTICAL per (pixel, code):
//     a  = np_sumsq64(x)
//     c  = sequential fmaf chain d=0..63 (per v2f component)
//     dk = fl( fl(a+b_k) - 2*c ),  argmin strict < (ascending code order)
// ---------------------------------------------------------------------------
__global__ __launch_bounds__(512, 2) void vq_main(const float* __restrict__ inp,
                                                  const float* __restrict__ weight,
                                                  const float* __restrict__ wsum,
                                                  float* __restrict__ out,
                                                  float* __restrict__ idx_out,
                                                  float* __restrict__ block_loss) {
    __shared__ float cbv[2][HALF_T];         // lower half's best values
    __shared__ int   cbk[2][HALF_T];         // lower half's best indices
    __shared__ float red[BLOCK / 64];

    const int tid  = threadIdx.x;
    // tid>>8 is constant within each 64-lane wave (waves are 64-aligned in a
    // 512 block); readfirstlane makes that uniformity visible to the compiler
    // so weight addresses become scalar (s_load) addresses.
    const int half = __builtin_amdgcn_readfirstlane(tid >> 8);
    const int t    = tid & 255;
    const int n0   = blockIdx.x * PIXBLK + t;
    const int n1   = n0 + HALF_T;
    const int b0 = n0 >> 12, hw0 = n0 & 4095;
    const int b1 = n1 >> 12, hw1 = n1 & 4095;

    const float* xb0 = inp + (size_t)b0 * CHW + hw0;
    const float* xb1 = inp + (size_t)b1 * CHW + hw1;
    v2f xp[DIM];
#pragma unroll
    for (int d = 0; d < DIM; ++d) {
        v2f v;
        v[0] = xb0[(size_t)d * HWSZ];
        v[1] = xb1[(size_t)d * HWSZ];
        xp[d] = v;
    }

    const float a0 = np_sumsq64_s2((const float*)xp, 0);
    const float a1 = np_sumsq64_s2((const float*)xp, 1);

    float best0 = 3.402823466e38f, best1 = 3.402823466e38f;
    int   bk0 = 0, bk1 = 0;

    const int kbase = half * KHALF;
    const float* __restrict__ wb = weight + (size_t)kbase * DIM;  // uniform base
    const float* __restrict__ ws = wsum + kbase;                  // uniform base

    float wA[32], wB[32];   // uniform -> SGPR-resident half-code buffers
#pragma unroll
    for (int j = 0; j < 32; ++j) wA[j] = wb[j];   // preload code 0, d=0..31

#pragma unroll 1
    for (int k = 0; k < KHALF; ++k) {
        const float bsw = ws[k];
        const int   kn  = (k + 1 < KHALF) ? (k + 1) : 0;   // guarded prefetch
        const float* rk  = wb + k * DIM;
        const float* rkn = wb + kn * DIM;

        // prefetch second half of current code while fma-ing the first
#pragma unroll
        for (int j = 0; j < 32; ++j) wB[j] = rk[32 + j];

        v2f c = {0.f, 0.f};
#pragma unroll
        for (int j = 0; j < 32; ++j) c = fma2(xp[j], wA[j], c);

        // prefetch first half of next code while fma-ing the second
#pragma unroll
        for (int j = 0; j < 32; ++j) wA[j] = rkn[j];

#pragma unroll
        for (int j = 0; j < 32; ++j) c = fma2(xp[32 + j], wB[j], c);

        float dk0, dk1;
        {
#pragma clang fp contract(off)
            const float sa = a0 + bsw;
            const float ta = a1 + bsw;
            dk0 = sa - 2.0f * c[0];
            dk1 = ta - 2.0f * c[1];
        }
        const int kg = kbase + k;
        if (dk0 < best0) { best0 = dk0; bk0 = kg; }
        if (dk1 < best1) { best1 = dk1; bk1 = kg; }
    }

    // ---- combine halves: lower publishes, upper resolves ----
    __syncthreads();
    if (half == 0) {
        cbv[0][t] = best0; cbk[0][t] = bk0;
        cbv[1][t] = best1; cbk[1][t] = bk1;
    }
    __syncthreads();

    float ls = 0.f;
    if (half == 1) {
        // upper wins only if strictly smaller (lower indices take ties)
        const float lo0 = cbv[0][t]; const int lk0 = cbk[0][t];
        const float lo1 = cbv[1][t]; const int lk1 = cbk[1][t];
        if (!(best0 < lo0)) { best0 = lo0; bk0 = lk0; }
        if (!(best1 < lo1)) { best1 = lo1; bk1 = lk1; }

        // Epilogue: gather winning code rows, write out, loss partials.
        const float* wb0 = weight + bk0 * DIM;   // per-lane gather, L2-hot
        const float* wb1 = weight + bk1 * DIM;
        float* ob0 = out + (size_t)b0 * CHW + hw0;
        float* ob1 = out + (size_t)b1 * CHW + hw1;
#pragma unroll
        for (int c = 0; c < DIM; ++c) {
            const float wv0 = wb0[c];
            ob0[(size_t)c * HWSZ] = wv0;
            const float d0 = wv0 - xp[c][0];
            ls = fmaf(d0, d0, ls);
            const float wv1 = wb1[c];
            ob1[(size_t)c * HWSZ] = wv1;
            const float d1 = wv1 - xp[c][1];
            ls = fmaf(d1, d1, ls);
        }
        idx_out[n0] = (float)bk0;
        idx_out[n1] = (float)bk1;
    }

    // Block reduction of loss partial (8 waves; lower waves contribute 0)
#pragma unroll
    for (int off = 32; off > 0; off >>= 1) ls += __shfl_down(ls, off, 64);
    const int lane = tid & 63;
    const int wid  = tid >> 6;
    if (lane == 0) red[wid] = ls;
    __syncthreads();
    if (tid == 0) {
        float s = 0.f;
#pragma unroll
        for (int w = 0; w < BLOCK / 64; ++w) s += red[w];
        block_loss[blockIdx.x] = s;
    }
}

// ---------------------------------------------------------------------------
// Kernel 2: reduce 256 block partials -> loss scalar
//   loss = q + 0.25*e = 1.25 * mean((quantized - x)^2)
// ---------------------------------------------------------------------------
__global__ __launch_bounds__(256) void vq_loss_reduce(const float* __restrict__ bl,
                                                      float* __restrict__ loss_out) {
    double s = 0.0;
    for (int i = threadIdx.x; i < NBLOCKS; i += 256) s += (double)bl[i];
    __shared__ double red[4];
#pragma unroll
    for (int off = 32; off > 0; off >>= 1) s += __shfl_down(s, off, 64);
    const int lane = threadIdx.x & 63;
    const int wid  = threadIdx.x >> 6;
    if (lane == 0) red[wid] = s;
    __syncthreads();
    if (threadIdx.x == 0) {
        const double total = (red[0] + red[1]) + (red[2] + red[3]);
        loss_out[0] = (float)(1.25 * total / (double)OUT_ELEMS);
    }
}

// ---------------------------------------------------------------------------
extern "C" void kernel_launch(void* const* d_in, const int* in_sizes, int n_in,
                              void* d_out, int out_size, void* d_ws, size_t ws_size,
                              hipStream_t stream) {
    const float* inp    = (const float*)d_in[0];   // [32,64,64,64] NCHW fp32
    const float* weight = (const float*)d_in[1];   // [1024,64] fp32

    float* out_q    = (float*)d_out;                         // 8388608 elems
    float* out_loss = (float*)d_out + OUT_ELEMS;             // 1 elem
    float* out_idx  = (float*)d_out + OUT_ELEMS + 1;         // 131072 elems

    float* wsum       = (float*)d_ws;                        // 1024 floats
    float* block_loss = (float*)d_ws + KCODES;               // 256 floats

    vq_wsum<<<KCODES / 256, 256, 0, stream>>>(weight, wsum);
    vq_main<<<NBLOCKS, BLOCK, 0, stream>>>(inp, weight, wsum,
                                           out_q, out_idx, block_loss);
    vq_loss_reduce<<<1, BLOCK / 2, 0, stream>>>(block_loss, out_loss);
}